// Round 1
// 1622.429 us; speedup vs baseline: 1.3371x; 1.3371x over previous
//
#include <hip/hip_runtime.h>

#define V_NUM 50000
#define C_IN  128
#define C_MID 256
#define C_OUT 128

typedef __attribute__((ext_vector_type(4))) float f32x4;
typedef __attribute__((ext_vector_type(8))) short short8;

// fp32 -> bf16 bits, round-to-nearest-even
__device__ __forceinline__ short f2bf(float f) {
    unsigned u = __builtin_bit_cast(unsigned, f);
    u = (u + 0x7FFFu + ((u >> 16) & 1u)) >> 16;
    return (short)u;
}
__device__ __forceinline__ float bf2f(short s) {
    return __builtin_bit_cast(float, ((unsigned)(unsigned short)s) << 16);
}

// order-preserving fp32 <-> u32 for atomicMax (monotone map)
__device__ __forceinline__ unsigned enc_f(float f) {
    unsigned u = __builtin_bit_cast(unsigned, f);
    return (u & 0x80000000u) ? ~u : (u | 0x80000000u);
}
// decode; non-finite (incl. the all-zero init == -NaN) -> 0.0f (matches reference fill)
__device__ __forceinline__ float dec0(unsigned e) {
    unsigned u = (e & 0x80000000u) ? (e & 0x7FFFFFFFu) : ~e;
    if ((u & 0x7F800000u) == 0x7F800000u) return 0.0f;
    return __builtin_bit_cast(float, u);
}

__device__ __forceinline__ short8 pack8(float4 a, float4 b) {
    short8 s;
    s[0] = f2bf(a.x); s[1] = f2bf(a.y); s[2] = f2bf(a.z); s[3] = f2bf(a.w);
    s[4] = f2bf(b.x); s[5] = f2bf(b.y); s[6] = f2bf(b.z); s[7] = f2bf(b.w);
    return s;
}

// ---------------------------------------------------------------------------
// Sort pass A: histogram of vertex ids
// ---------------------------------------------------------------------------
__global__ __launch_bounds__(256) void khist(const int* __restrict__ vid,
                                             unsigned* __restrict__ counts, int E) {
    int e = blockIdx.x * 256 + threadIdx.x;
    if (e < E) atomicAdd(&counts[vid[e]], 1u);
}

// ---------------------------------------------------------------------------
// Sort pass B: exclusive prefix-scan of counts -> cursor (single block)
// ---------------------------------------------------------------------------
__global__ __launch_bounds__(1024) void kscan(const unsigned* __restrict__ counts,
                                              unsigned* __restrict__ cursor) {
    __shared__ unsigned wsum[16];
    __shared__ unsigned carry;
    const int t = threadIdx.x, lane = t & 63, w = t >> 6;
    if (t == 0) carry = 0u;
    __syncthreads();
    for (int base = 0; base < V_NUM; base += 1024) {
        int i = base + t;
        unsigned c = (i < V_NUM) ? counts[i] : 0u;
        unsigned x = c;
#pragma unroll
        for (int d = 1; d < 64; d <<= 1) {
            unsigned v = __shfl_up(x, d, 64);
            if (lane >= d) x += v;
        }
        __syncthreads();                 // prior iteration's wsum consumers done
        if (lane == 63) wsum[w] = x;
        __syncthreads();                 // wsum visible
        unsigned off = carry;
        for (int j = 0; j < w; ++j) off += wsum[j];
        if (i < V_NUM) cursor[i] = off + x - c;   // exclusive
        __syncthreads();                 // all carry/wsum reads done
        if (t == 0) {
            unsigned tot = 0;
#pragma unroll
            for (int j = 0; j < 16; ++j) tot += wsum[j];
            carry += tot;
        }
    }
}

// ---------------------------------------------------------------------------
// Sort pass C: scatter edge indices into vertex-sorted order
// ---------------------------------------------------------------------------
__global__ __launch_bounds__(256) void kscatter(const int* __restrict__ vid,
                                                unsigned* __restrict__ cursor,
                                                int* __restrict__ perm,
                                                int* __restrict__ vids, int E) {
    int e = blockIdx.x * 256 + threadIdx.x;
    if (e < E) {
        int v = vid[e];
        unsigned p = atomicAdd(&cursor[v], 1u);
        perm[p] = e;
        vids[p] = v;
    }
}

// ---------------------------------------------------------------------------
// Pass 1: z = x[perm] @ W1^T + b1 on 64 vertex-sorted edges, then in-LDS
//         per-channel segmented max; one atomicMax per (run, channel).
// block = 256 threads (4 waves); wave w owns mid-channels [64w, 64w+64)
// ---------------------------------------------------------------------------
__global__ __launch_bounds__(256) void k1_gemm_seg(
    const float* __restrict__ x, const int* __restrict__ perm,
    const int* __restrict__ vids, const float* __restrict__ W1,
    const float* __restrict__ b1, unsigned* __restrict__ enc, int E)
{
    // union: sA = 64x128 bf16 pitch 136 (8704 shorts); zb = 64x256 bf16 pitch 264
    __shared__ __align__(16) short smem[64 * 264];
    __shared__ int sP[64], sV[64];
    short* sA = smem;
    short* zb = smem;
    const int t = threadIdx.x;
    const long i0 = (long)blockIdx.x * 64;

    if (t < 64) {
        long i = i0 + t;
        int ok = (i < E);
        sP[t] = ok ? perm[i] : -1;
        sV[t] = ok ? vids[i] : -1;
    }
    __syncthreads();

    // stage gathered x rows as bf16 (each row = 512B contiguous)
#pragma unroll
    for (int it = 0; it < 8; ++it) {
        int f4 = it * 256 + t;           // row = f4/32, col4 = f4%32
        int row = f4 >> 5, c4 = f4 & 31;
        int p = sP[row];
        float4 v = {0.f, 0.f, 0.f, 0.f};
        if (p >= 0) v = *(const float4*)(x + (long)p * C_IN + c4 * 4);
        short* d = &sA[row * 136 + c4 * 4];
        d[0] = f2bf(v.x); d[1] = f2bf(v.y); d[2] = f2bf(v.z); d[3] = f2bf(v.w);
    }
    __syncthreads();

    const int lane = t & 63, wave = t >> 6;
    const int r = lane & 15, q = lane >> 4;
    const int nb = wave * 64;

    f32x4 acc[4][4] = {};   // [mf][nf]
#pragma unroll
    for (int ks = 0; ks < 4; ++ks) {
        const int k0 = ks * 32 + q * 8;
        short8 a[4], b[4];
#pragma unroll
        for (int mf = 0; mf < 4; ++mf)
            a[mf] = *(const short8*)&sA[(mf * 16 + r) * 136 + k0];
#pragma unroll
        for (int nf = 0; nf < 4; ++nf) {
            const float* wp = W1 + (nb + nf * 16 + r) * C_IN + k0;
            b[nf] = pack8(*(const float4*)wp, *(const float4*)(wp + 4));
        }
#pragma unroll
        for (int mf = 0; mf < 4; ++mf)
#pragma unroll
            for (int nf = 0; nf < 4; ++nf)
                acc[mf][nf] = __builtin_amdgcn_mfma_f32_16x16x32_bf16(
                    a[mf], b[nf], acc[mf][nf], 0, 0, 0);
    }

    __syncthreads();   // all waves done reading sA; smem becomes zb

    float bias[4];
#pragma unroll
    for (int nf = 0; nf < 4; ++nf) bias[nf] = b1[nb + nf * 16 + r];

    // C/D layout: col = lane&15 (=r), row = q*4 + reg
#pragma unroll
    for (int mf = 0; mf < 4; ++mf) {
#pragma unroll
        for (int rg = 0; rg < 4; ++rg) {
            int m = mf * 16 + q * 4 + rg;
            short* d = &zb[m * 264 + nb + r];
#pragma unroll
            for (int nf = 0; nf < 4; ++nf)
                d[nf * 16] = f2bf(acc[mf][nf][rg] + bias[nf]);
        }
    }
    __syncthreads();

    // per-channel segmented max over 64 sorted rows; flush on vid change
    const int ch = t;                 // 0..255
    int cur = -1;
    float m = -3.0e38f;
    for (int row = 0; row < 64; ++row) {
        int v = sV[row];              // wave-uniform -> scalar branch
        if (v != cur) {
            if (cur >= 0) atomicMax(&enc[(long)cur * C_MID + ch], enc_f(m));
            cur = v;
            m = -3.0e38f;
        }
        m = fmaxf(m, bf2f(zb[row * 264 + ch]));
    }
    if (cur >= 0) atomicMax(&enc[(long)cur * C_MID + ch], enc_f(m));
}

// ---------------------------------------------------------------------------
// Pass 2: z_vertex = dec(z_vmax) @ W2v^T   (V x 256) @ (256 x 128)
// ---------------------------------------------------------------------------
__global__ __launch_bounds__(256) void k2_vertex_gemm(
    const unsigned* __restrict__ enc, const float* __restrict__ W2v,
    float* __restrict__ zv)
{
    __shared__ __align__(16) short sA[64 * 264];  // 64 x 256 bf16, pitch +8
    const int t = threadIdx.x;
    const long v0 = (long)blockIdx.x * 64;

#pragma unroll
    for (int i = 0; i < 16; ++i) {
        int f4 = i * 256 + t;            // row = f4/64, col4 = f4%64
        int row = f4 >> 6, c4 = f4 & 63;
        long v = v0 + row;
        float w0 = 0.f, w1 = 0.f, w2 = 0.f, w3 = 0.f;
        if (v < V_NUM) {
            uint4 e = *(const uint4*)(enc + v * C_MID + c4 * 4);
            w0 = dec0(e.x); w1 = dec0(e.y); w2 = dec0(e.z); w3 = dec0(e.w);
        }
        short* d = &sA[row * 264 + c4 * 4];
        d[0] = f2bf(w0); d[1] = f2bf(w1); d[2] = f2bf(w2); d[3] = f2bf(w3);
    }
    __syncthreads();

    const int lane = t & 63, wave = t >> 6;
    const int r = lane & 15, q = lane >> 4;
    const int nb = wave * 32;

    f32x4 acc[4][2] = {};
#pragma unroll
    for (int ks = 0; ks < 8; ++ks) {
        const int k0 = ks * 32 + q * 8;
        short8 a[4], b[2];
#pragma unroll
        for (int mf = 0; mf < 4; ++mf)
            a[mf] = *(const short8*)&sA[(mf * 16 + r) * 264 + k0];
#pragma unroll
        for (int nf = 0; nf < 2; ++nf) {
            const float* wp = W2v + (nb + nf * 16 + r) * C_MID + k0;
            b[nf] = pack8(*(const float4*)wp, *(const float4*)(wp + 4));
        }
#pragma unroll
        for (int mf = 0; mf < 4; ++mf)
#pragma unroll
            for (int nf = 0; nf < 2; ++nf)
                acc[mf][nf] = __builtin_amdgcn_mfma_f32_16x16x32_bf16(
                    a[mf], b[nf], acc[mf][nf], 0, 0, 0);
    }

#pragma unroll
    for (int mf = 0; mf < 4; ++mf) {
#pragma unroll
        for (int rg = 0; rg < 4; ++rg) {
            long v = v0 + mf * 16 + q * 4 + rg;
            if (v < V_NUM) {
#pragma unroll
                for (int nf = 0; nf < 2; ++nf)
                    zv[v * C_OUT + nb + nf * 16 + r] = acc[mf][nf][rg];
            }
        }
    }
}

// ---------------------------------------------------------------------------
// Pass 3: out = x @ W2e^T + z_vertex[vid]; zv rows staged through LDS
// ---------------------------------------------------------------------------
__global__ __launch_bounds__(256) void k3_out(
    const float* __restrict__ x, const int* __restrict__ vid,
    const float* __restrict__ W2e, const float* __restrict__ zv,
    float* __restrict__ out, int E)
{
    __shared__ __align__(16) short sA[64 * 136];
    __shared__ __align__(16) float sZ[64 * 132];   // 64 x 128 f32, pitch +4
    __shared__ int sV[64];
    const int t = threadIdx.x;
    const long e0 = (long)blockIdx.x * 64;

    if (t < 64) sV[t] = (e0 + t < E) ? vid[e0 + t] : 0;

    const float4* xg = (const float4*)(x + e0 * C_IN);
#pragma unroll
    for (int i = 0; i < 8; ++i) {
        int f4 = i * 256 + t;
        int row = f4 >> 5, c4 = f4 & 31;
        float4 v = (e0 + row < E) ? xg[f4] : float4{0.f, 0.f, 0.f, 0.f};
        short* d = &sA[row * 136 + c4 * 4];
        d[0] = f2bf(v.x); d[1] = f2bf(v.y); d[2] = f2bf(v.z); d[3] = f2bf(v.w);
    }
    __syncthreads();

    // cooperative gather of zv rows (each row = 512B contiguous float4s)
#pragma unroll
    for (int i = 0; i < 8; ++i) {
        int f4 = i * 256 + t;
        int row = f4 >> 5, c4 = f4 & 31;
        float4 v = *(const float4*)(zv + (long)sV[row] * C_OUT + c4 * 4);
        *(float4*)&sZ[row * 132 + c4 * 4] = v;
    }

    const int lane = t & 63, wave = t >> 6;
    const int r = lane & 15, q = lane >> 4;
    const int nb = wave * 32;

    f32x4 acc[4][2] = {};
#pragma unroll
    for (int ks = 0; ks < 4; ++ks) {
        const int k0 = ks * 32 + q * 8;
        short8 a[4], b[2];
#pragma unroll
        for (int mf = 0; mf < 4; ++mf)
            a[mf] = *(const short8*)&sA[(mf * 16 + r) * 136 + k0];
#pragma unroll
        for (int nf = 0; nf < 2; ++nf) {
            const float* wp = W2e + (nb + nf * 16 + r) * C_IN + k0;
            b[nf] = pack8(*(const float4*)wp, *(const float4*)(wp + 4));
        }
#pragma unroll
        for (int mf = 0; mf < 4; ++mf)
#pragma unroll
            for (int nf = 0; nf < 2; ++nf)
                acc[mf][nf] = __builtin_amdgcn_mfma_f32_16x16x32_bf16(
                    a[mf], b[nf], acc[mf][nf], 0, 0, 0);
    }

    __syncthreads();   // sZ staging (pre-MFMA) complete for all threads

#pragma unroll
    for (int mf = 0; mf < 4; ++mf) {
#pragma unroll
        for (int rg = 0; rg < 4; ++rg) {
            int m = mf * 16 + q * 4 + rg;
            long e = e0 + m;
            if (e < E) {
#pragma unroll
                for (int nf = 0; nf < 2; ++nf) {
                    int n = nb + nf * 16 + r;
                    out[e * C_OUT + n] = acc[mf][nf][rg] + sZ[m * 132 + n];
                }
            }
        }
    }
}

extern "C" void kernel_launch(void* const* d_in, const int* in_sizes, int n_in,
                              void* d_out, int out_size, void* d_ws, size_t ws_size,
                              hipStream_t stream) {
    const float* x   = (const float*)d_in[0];
    const int*   vid = (const int*)d_in[1];
    const float* W1  = (const float*)d_in[2];
    const float* b1  = (const float*)d_in[3];
    const float* W2e = (const float*)d_in[4];
    const float* W2v = (const float*)d_in[5];
    float* out = (float*)d_out;
    const int E = in_sizes[1];

    // workspace layout (76.8 MB total, same footprint as before):
    //   [0, 25.6MB)      zv (V x 128 f32), written by k2 -- early in the
    //                    pipeline this region is dead, so the sort scratch
    //                    aliases it:
    //                      counts @ 0      (V u32)
    //                      cursor @ 1MiB   (V u32)
    //                      perm   @ 2MiB   (E i32)
    //                      vids   @ 8MiB   (E i32)
    //   [25.6MB, 76.8MB) enc (V x 256 u32 encoded-max table)
    char* ws = (char*)d_ws;
    float*    zv     = (float*)ws;
    unsigned* counts = (unsigned*)ws;
    unsigned* cursor = (unsigned*)(ws + (1u << 20));
    int*      perm   = (int*)(ws + (2u << 20));
    int*      vids   = (int*)(ws + (8u << 20));
    unsigned* enc    = (unsigned*)(ws + (size_t)V_NUM * C_OUT * 4);

    hipMemsetAsync(counts, 0, (size_t)V_NUM * sizeof(unsigned), stream);
    hipMemsetAsync(enc, 0, (size_t)V_NUM * C_MID * sizeof(unsigned), stream);

    const int nb256  = (E + 255) / 256;
    const int nblk_e = (E + 63) / 64;
    const int nblk_v = (V_NUM + 63) / 64;

    khist<<<nb256, 256, 0, stream>>>(vid, counts, E);
    kscan<<<1, 1024, 0, stream>>>(counts, cursor);
    kscatter<<<nb256, 256, 0, stream>>>(vid, cursor, perm, vids, E);
    k1_gemm_seg<<<nblk_e, 256, 0, stream>>>(x, perm, vids, W1, b1, enc, E);
    k2_vertex_gemm<<<nblk_v, 256, 0, stream>>>(enc, W2v, zv);
    k3_out<<<nblk_e, 256, 0, stream>>>(x, vid, W2e, zv, out, E);
}